// Round 1
// baseline (885.113 us; speedup 1.0000x reference)
//
#include <hip/hip_runtime.h>
#include <hip/hip_bf16.h>

// NNConv GNN refactored:
//   Instead of per-edge W[e] (E x 64 x 64 = 1.6 GB), note
//   msg[e] = h[src] @ (sum_k ek[e][k] K_k + B)  =  sum_k ek[e][k] (h[src]@K_k) + h[src]@B
//   so compute P = h @ [K_0|...|K_15|B|root_w]  ([N,64]@[64,1152]) once per layer,
//   then each edge does a rank-17 combine of P rows + atomic scatter to agg.

#define N_NODES 20000
#define N_EDGES 100000
#define WIDTH   64
#define KH      16
#define NB      18          // 16 kernel blocks + bias block + root block
#define PC      (NB * 64)   // 1152
#define BIAS_OFF (16 * 64)  // 1024
#define ROOT_OFF (17 * 64)  // 1088
#define DEPTH   6

// ---------------- ek + degree ----------------
__global__ __launch_bounds__(256) void ek_deg_kernel(
    const float* __restrict__ edge_attr, const float* __restrict__ k1_w,
    const float* __restrict__ k1_b, const int* __restrict__ ei,
    float* __restrict__ ek, float* __restrict__ deg)
{
    int e = blockIdx.x * 256 + threadIdx.x;
    if (e >= N_EDGES) return;
    float a[6];
#pragma unroll
    for (int i = 0; i < 6; ++i) a[i] = edge_attr[e * 6 + i];
#pragma unroll
    for (int j = 0; j < 16; ++j) {
        float s = k1_b[j];
#pragma unroll
        for (int i = 0; i < 6; ++i) s = fmaf(a[i], k1_w[i * 16 + j], s);
        ek[e * 16 + j] = fmaxf(s, 0.f);
    }
    atomicAdd(&deg[ei[N_EDGES + e]], 1.0f);
}

// ---------------- 1/max(deg,1) ----------------
__global__ __launch_bounds__(256) void invden_kernel(float* __restrict__ deg,
                                                     float* __restrict__ invd)
{
    int n = blockIdx.x * 256 + threadIdx.x;
    if (n >= N_NODES) return;
    invd[n] = 1.0f / fmaxf(deg[n], 1.0f);
}

// ---------------- build Gw [64 x 1152] ----------------
__global__ __launch_bounds__(256) void build_gw_kernel(
    const float* __restrict__ k2_w, const float* __restrict__ k2_b,
    const float* __restrict__ root_w, float* __restrict__ Gw)
{
    int idx = blockIdx.x * 256 + threadIdx.x;   // 64*1152 = 73728 total
    if (idx >= 64 * PC) return;
    int i = idx / PC;        // input feature 0..63
    int c = idx % PC;        // output column 0..1151
    int b = c >> 6;          // block 0..17
    int o = c & 63;
    float v;
    if (b < 16)       v = k2_w[b * 4096 + i * 64 + o];  // k2_w[k][i*64+o]
    else if (b == 16) v = k2_b[i * 64 + o];
    else              v = root_w[i * 64 + o];
    Gw[idx] = v;
}

// ---------------- h0 = x * fc1_w + fc1_b ----------------
__global__ __launch_bounds__(256) void h0_kernel(
    const float* __restrict__ x, const float* __restrict__ fc1_w,
    const float* __restrict__ fc1_b, float* __restrict__ h)
{
    int idx = blockIdx.x * 256 + threadIdx.x;
    if (idx >= N_NODES * WIDTH) return;
    int n = idx >> 6, o = idx & 63;
    h[idx] = fmaf(x[n], fc1_w[o], fc1_b[o]);
}

// ---------------- P = h @ Gw   [20000,64] @ [64,1152] ----------------
// block: 256 threads = 64 col-lanes x 4 row groups; tile = 32 nodes x 192 cols
__global__ __launch_bounds__(256) void gemm_kernel(
    const float* __restrict__ h, const float* __restrict__ Gw,
    float* __restrict__ P)
{
    __shared__ float hs[32][64];
    int n0 = blockIdx.x * 32;          // 625 blocks exactly covers 20000
    int c0 = blockIdx.y * 192;         // 6 tiles covers 1152
    int t = threadIdx.x;
    for (int idx = t; idx < 32 * 64; idx += 256) {
        int r = idx >> 6, i = idx & 63;
        hs[r][i] = h[(n0 + r) * 64 + i];
    }
    __syncthreads();
    int lc = t & 63;   // column lane
    int rs = t >> 6;   // node sub-group 0..3 (8 nodes each)
    float acc[8][3] = {};
    for (int i = 0; i < 64; ++i) {
        float g0 = Gw[i * PC + c0 + lc];
        float g1 = Gw[i * PC + c0 + 64 + lc];
        float g2 = Gw[i * PC + c0 + 128 + lc];
        float hv[8];
#pragma unroll
        for (int j = 0; j < 8; ++j) hv[j] = hs[rs * 8 + j][i];
#pragma unroll
        for (int j = 0; j < 8; ++j) {
            acc[j][0] = fmaf(hv[j], g0, acc[j][0]);
            acc[j][1] = fmaf(hv[j], g1, acc[j][1]);
            acc[j][2] = fmaf(hv[j], g2, acc[j][2]);
        }
    }
#pragma unroll
    for (int j = 0; j < 8; ++j) {
        int n = n0 + rs * 8 + j;
#pragma unroll
        for (int cc = 0; cc < 3; ++cc)
            P[(size_t)n * PC + c0 + cc * 64 + lc] = acc[j][cc];
    }
}

// ---------------- edge pass: msg + atomic scatter ----------------
// one wave per edge; lane = output channel
__global__ __launch_bounds__(256) void edge_kernel(
    const int* __restrict__ ei, const float* __restrict__ ek,
    const float* __restrict__ P, float* __restrict__ agg)
{
    int wave = blockIdx.x * 4 + (threadIdx.x >> 6);   // 25000*4 = 100000 exact
    int lane = threadIdx.x & 63;
    int src = ei[wave];
    int dst = ei[N_EDGES + wave];
    const float* Pr = P + (size_t)src * PC;
    // lanes 0..15 fetch the 16 edge-kernel weights, broadcast via shfl
    float ekv = (lane < 16) ? ek[wave * 16 + lane] : 0.f;
    float msg = Pr[BIAS_OFF + lane];
#pragma unroll
    for (int k = 0; k < 16; ++k) {
        float w = __shfl(ekv, k, 64);
        msg = fmaf(w, Pr[k * 64 + lane], msg);
    }
    atomicAdd(&agg[dst * 64 + lane], msg);
}

// ---------------- node update: h = relu(agg/den + P_root + conv_b) ----------------
__global__ __launch_bounds__(256) void node_update_kernel(
    const float* __restrict__ agg, const float* __restrict__ invd,
    const float* __restrict__ P, const float* __restrict__ conv_b,
    float* __restrict__ h)
{
    int idx = blockIdx.x * 256 + threadIdx.x;
    if (idx >= N_NODES * WIDTH) return;
    int n = idx >> 6, o = idx & 63;
    float v = fmaf(agg[idx], invd[n], P[(size_t)n * PC + ROOT_OFF + o] + conv_b[o]);
    h[idx] = fmaxf(v, 0.f);
}

// ---------------- out = h @ fc2_w + fc2_b ----------------
__global__ __launch_bounds__(256) void out_kernel(
    const float* __restrict__ h, const float* __restrict__ fc2_w,
    const float* __restrict__ fc2_b, float* __restrict__ out)
{
    int wave = blockIdx.x * 4 + (threadIdx.x >> 6);   // 5000*4 = 20000 exact
    int lane = threadIdx.x & 63;
    float v = h[wave * 64 + lane] * fc2_w[lane];
#pragma unroll
    for (int off = 32; off > 0; off >>= 1) v += __shfl_down(v, off);
    if (lane == 0) out[wave] = v + fc2_b[0];
}

extern "C" void kernel_launch(void* const* d_in, const int* in_sizes, int n_in,
                              void* d_out, int out_size, void* d_ws, size_t ws_size,
                              hipStream_t stream)
{
    const float* x         = (const float*)d_in[0];
    const int*   ei        = (const int*)  d_in[1];
    const float* edge_attr = (const float*)d_in[2];
    const float* fc1_w     = (const float*)d_in[3];
    const float* fc1_b     = (const float*)d_in[4];
    const float* k1_w      = (const float*)d_in[5];
    const float* k1_b      = (const float*)d_in[6];
    const float* k2_w      = (const float*)d_in[7];
    const float* k2_b      = (const float*)d_in[8];
    const float* root_w    = (const float*)d_in[9];
    const float* conv_b    = (const float*)d_in[10];
    const float* fc2_w     = (const float*)d_in[11];
    const float* fc2_b     = (const float*)d_in[12];
    float* out = (float*)d_out;

    // workspace layout (floats): total ~27.3M floats = ~104 MiB
    float* ws   = (float*)d_ws;
    float* ek   = ws;                        // E*16      = 1,600,000
    float* Gw   = ek   + (size_t)N_EDGES*16; // 64*1152   = 73,728
    float* h    = Gw   + 64 * PC;            // N*64      = 1,280,000
    float* agg  = h    + (size_t)N_NODES*64; // N*64      = 1,280,000
    float* deg  = agg  + (size_t)N_NODES*64; // N         = 20,000
    float* invd = deg  + N_NODES;            // N         = 20,000
    float* P    = invd + N_NODES;            // N*1152    = 23,040,000

    hipMemsetAsync(deg, 0, N_NODES * sizeof(float), stream);
    ek_deg_kernel<<<(N_EDGES + 255) / 256, 256, 0, stream>>>(edge_attr, k1_w, k1_b, ei, ek, deg);
    invden_kernel<<<(N_NODES + 255) / 256, 256, 0, stream>>>(deg, invd);
    build_gw_kernel<<<(64 * PC + 255) / 256, 256, 0, stream>>>(k2_w, k2_b, root_w, Gw);
    h0_kernel<<<(N_NODES * WIDTH + 255) / 256, 256, 0, stream>>>(x, fc1_w, fc1_b, h);

    for (int layer = 0; layer < DEPTH; ++layer) {
        gemm_kernel<<<dim3(N_NODES / 32, PC / 192), 256, 0, stream>>>(h, Gw, P);
        hipMemsetAsync(agg, 0, (size_t)N_NODES * WIDTH * sizeof(float), stream);
        edge_kernel<<<N_EDGES / 4, 256, 0, stream>>>(ei, ek, P, agg);
        node_update_kernel<<<(N_NODES * WIDTH + 255) / 256, 256, 0, stream>>>(agg, invd, P, conv_b, h);
    }

    out_kernel<<<N_NODES / 4, 256, 0, stream>>>(h, fc2_w, fc2_b, out);
}